// Round 3
// baseline (395.062 us; speedup 1.0000x reference)
//
#include <hip/hip_runtime.h>

#define HD 4096

typedef __attribute__((ext_vector_type(4))) float f32x4;
typedef __attribute__((ext_vector_type(8))) short bf16x8;
typedef __attribute__((ext_vector_type(4))) short s16x4;
typedef __attribute__((ext_vector_type(2))) unsigned u32x2;

__device__ __forceinline__ short f2bf(float f) {
    unsigned u = __float_as_uint(f);
    u += 0x7fffu + ((u >> 16) & 1u);   // RNE (finite inputs)
    return (short)(u >> 16);
}

__device__ __forceinline__ float sigmoidf_(float x) { return 1.f / (1.f + __expf(-x)); }

// ---------------------------------------------------------------------------
// fp32 activations -> bf16. X: 65536 f32x4, h0: 131072 f32x4. Grid 768x256.
// ---------------------------------------------------------------------------
__global__ void convert_kernel(const float* __restrict__ X, const float* __restrict__ h0,
                               short* __restrict__ Xbf, short* __restrict__ H0bf)
{
    const int i = blockIdx.x * blockDim.x + threadIdx.x;
    if (i < 65536) {
        f32x4 v = ((const f32x4*)X)[i];
        s16x4 o = { f2bf(v[0]), f2bf(v[1]), f2bf(v[2]), f2bf(v[3]) };
        ((s16x4*)Xbf)[i] = o;
    } else {
        const int j = i - 65536;
        f32x4 v = ((const f32x4*)h0)[j];
        s16x4 o = { f2bf(v[0]), f2bf(v[1]), f2bf(v[2]), f2bf(v[3]) };
        ((s16x4*)H0bf)[j] = o;
    }
}

// ---------------------------------------------------------------------------
// Partial GEMM: P[kq][64][N] = A(bf16)[64][K-slice] @ W(fp32)^T.
// K_STEP=256 floats: each W row is visited in 1KB contiguous chunks (full
// DRAM page per visit) instead of 256B strided nibbles.
// Per-wave-private pipeline, NO barriers:
//   global fp32 -> regs (16 x dwordx4/thread) -> cvt_pk bf16 -> LDS dbuf.
// Wave w stages and reads only rows [16w,16w+16). LDS bf16 tile XOR-swizzled
// (granule ^= row&7) so ds_read_b128 B-frags are conflict-free.
// ---------------------------------------------------------------------------
#define ISSUE(TT) do { \
    const float* gp_ = gsrc + (long)(TT) * 256; \
    _Pragma("unroll") for (int j_ = 0; j_ < 16; ++j_) \
        sreg[j_] = *(const f32x4*)(gp_ + j_ * 16); \
    __builtin_amdgcn_sched_barrier(0); \
} while (0)

#define CVTWRITE(BUF) do { \
    char* lb_ = (char*)&wlds[wv][(BUF)][0] + row * 512 + (sub & 1) * 8; \
    _Pragma("unroll") for (int j_ = 0; j_ < 16; ++j_) { \
        unsigned lo_, hi_; \
        asm("v_cvt_pk_bf16_f32 %0, %1, %2" : "=v"(lo_) : "v"(sreg[j_][0]), "v"(sreg[j_][1])); \
        asm("v_cvt_pk_bf16_f32 %0, %1, %2" : "=v"(hi_) : "v"(sreg[j_][2]), "v"(sreg[j_][3])); \
        const int g_ = ((sub >> 1) + j_ * 2) ^ (row & 7); \
        u32x2 v_ = { lo_, hi_ }; \
        *(u32x2*)(lb_ + g_ * 16) = v_; \
    } \
} while (0)

#define COMPUTE(T_, BUF) do { \
    const short* ab_ = aBase + (long)(T_) * 256; \
    const char* lr_ = (const char*)&wlds[wv][(BUF)][0] + ar * 512; \
    _Pragma("unroll") for (int ks_ = 0; ks_ < 8; ++ks_) { \
        const int g_ = (ks_ * 4 + kg) ^ (ar & 7); \
        const bf16x8 b_ = *(const bf16x8*)(lr_ + g_ * 16); \
        _Pragma("unroll") for (int m_ = 0; m_ < 4; ++m_) { \
            const bf16x8 a_ = *(const bf16x8*)(ab_ + m_ * 16 * HD + ks_ * 32); \
            acc[m_] = __builtin_amdgcn_mfma_f32_16x16x32_bf16(a_, b_, acc[m_], 0, 0, 0); \
        } \
    } \
} while (0)

__global__ __launch_bounds__(256, 2) void gemm_part_kernel(
    const short* __restrict__ A0, const short* __restrict__ A1,
    const float* __restrict__ W0, const float* __restrict__ W1,
    float* __restrict__ P, int N, int nkq, int KB)
{
    __shared__ short wlds[4][2][4096];   // [wave][buf][16 rows x 256 k bf16] = 64 KB
    const int tid = threadIdx.x, lane = tid & 63, wv = tid >> 6;
    const int ar = lane & 15, kg = lane >> 4;     // MFMA fragment coords
    const int row = lane >> 2, sub = lane & 3;    // staging coords (row 0..15)
    const int bid = blockIdx.x;
    const int ntile = bid / nkq, kq = bid % nkq;
    const int half = nkq >> 1;
    const int kqh = (kq >= half) ? 1 : 0;
    const int kqi = kq - kqh * half;
    const short* A = kqh ? A1 : A0;
    const float* W = kqh ? W1 : W0;
    const int kbase = kqi * KB;
    const int T = KB >> 8;                        // tiles of 256 k
    const int n0w = ntile * 64 + wv * 16;

    const float* gsrc = W + (long)(n0w + row) * HD + kbase + sub * 4;
    const short* aBase = A + (long)ar * HD + kbase + kg * 8;

    const f32x4 zero = {0.f, 0.f, 0.f, 0.f};
    f32x4 acc[4] = {zero, zero, zero, zero};
    f32x4 sreg[16];

    // prologue
    ISSUE(0);
    asm volatile("s_waitcnt vmcnt(0)" ::: "memory");
    __builtin_amdgcn_sched_barrier(0);
    CVTWRITE(0);
    if (T > 1) ISSUE(1);
    asm volatile("s_waitcnt lgkmcnt(0)" ::: "memory");
    __builtin_amdgcn_sched_barrier(0);

    for (int t = 0; t < T; ++t) {
        COMPUTE(t, t & 1);
        if (t + 1 < T) {
            asm volatile("s_waitcnt vmcnt(0)" ::: "memory");
            __builtin_amdgcn_sched_barrier(0);
            CVTWRITE((t + 1) & 1);
            if (t + 2 < T) ISSUE(t + 2);
            asm volatile("s_waitcnt lgkmcnt(0)" ::: "memory");
            __builtin_amdgcn_sched_barrier(0);
        }
    }

    // write partial: P[kq][brow][col], brow = m*16 + kg*4 + r, col = n0w + ar
    float* pr = P + (long)kq * 64 * N + n0w + ar;
    #pragma unroll
    for (int m = 0; m < 4; ++m)
        #pragma unroll
        for (int r = 0; r < 4; ++r)
            pr[(long)(m * 16 + kg * 4 + r) * N] = acc[m][r];
}

// ---------------------------------------------------------------------------
// Reduce nkq partials + biases + LSTM cell. 65536 threads, f32x4 per thread.
// P layout: [nkq][64][16384], gates i,f,g,o at col g*4096 + hc.
// ---------------------------------------------------------------------------
__global__ void cell_kernel(const float* __restrict__ P, int nkq,
                            const float* __restrict__ bi, const float* __restrict__ bh,
                            const float* __restrict__ cprev,
                            float* __restrict__ hout, float* __restrict__ cout,
                            float* __restrict__ ms, short* __restrict__ hbf)
{
    const int idx = blockIdx.x * blockDim.x + threadIdx.x;  // 0..65535
    const int b = idx >> 10;
    const int hc = (idx & 1023) * 4;

    f32x4 g[4] = {{0,0,0,0},{0,0,0,0},{0,0,0,0},{0,0,0,0}};
    for (int kq = 0; kq < nkq; ++kq) {
        const float* pb = P + ((long)kq * 64 + b) * 16384 + hc;
        #pragma unroll
        for (int gt = 0; gt < 4; ++gt)
            g[gt] += *(const f32x4*)(pb + gt * 4096);
    }
    #pragma unroll
    for (int gt = 0; gt < 4; ++gt) {
        g[gt] += *(const f32x4*)(bi + gt * HD + hc);
        g[gt] += *(const f32x4*)(bh + gt * HD + hc);
    }
    const long off = (long)b * HD + hc;
    f32x4 c = *(const f32x4*)(cprev + off);
    f32x4 hn, cn; s16x4 hb;
    #pragma unroll
    for (int e = 0; e < 4; ++e) {
        float cv = sigmoidf_(g[1][e]) * c[e] + sigmoidf_(g[0][e]) * tanhf(g[2][e]);
        float hv = sigmoidf_(g[3][e]) * tanhf(cv);
        cn[e] = cv; hn[e] = hv; hb[e] = f2bf(hv);
    }
    *(f32x4*)(hout + off) = hn;
    *(f32x4*)(cout + off) = cn;
    if (ms) *(f32x4*)(ms + off) = hn;
    *(s16x4*)(hbf + off) = hb;
}

// ---------------------------------------------------------------------------
// Head finish: hid[b][n] = relu(sum_kq P[kq][b][n] + bc1[n]). N=2048.
// ---------------------------------------------------------------------------
__global__ void headfin_kernel(const float* __restrict__ P, int nkq,
                               const float* __restrict__ bc1, float* __restrict__ hid)
{
    const int idx = blockIdx.x * blockDim.x + threadIdx.x;  // 0..32767
    const int b = idx >> 9;
    const int n = (idx & 511) * 4;
    f32x4 s = {0.f, 0.f, 0.f, 0.f};
    for (int kq = 0; kq < nkq; ++kq)
        s += *(const f32x4*)(P + ((long)kq * 64 + b) * 2048 + n);
    s += *(const f32x4*)(bc1 + n);
    #pragma unroll
    for (int e = 0; e < 4; ++e) s[e] = fmaxf(s[e], 0.f);
    *(f32x4*)(hid + (long)b * 2048 + n) = s;
}

// ---------------------------------------------------------------------------
// count = relu(hid @ Wc2^T + bc2). [64,2048] x [2048] -> [64].
// ---------------------------------------------------------------------------
__global__ void count_kernel(const float* __restrict__ hid, const float* __restrict__ Wc2,
                             const float* __restrict__ bc2, float* __restrict__ out)
{
    const int tid = threadIdx.x;
    const int b = tid >> 2, q = tid & 3;
    const float* hp = hid + (long)b * 2048 + q * 512;
    const float* wp = Wc2 + q * 512;
    float s = 0.f;
    #pragma unroll 4
    for (int k = 0; k < 512; k += 4) {
        f32x4 h4 = *(const f32x4*)(hp + k);
        f32x4 w4 = *(const f32x4*)(wp + k);
        s += h4[0] * w4[0] + h4[1] * w4[1] + h4[2] * w4[2] + h4[3] * w4[3];
    }
    s += __shfl_xor(s, 1);
    s += __shfl_xor(s, 2);
    if (q == 0) out[b] = fmaxf(s + bc2[0], 0.f);
}

// ---------------------------------------------------------------------------
extern "C" void kernel_launch(void* const* d_in, const int* in_sizes, int n_in,
                              void* d_out, int out_size, void* d_ws, size_t ws_size,
                              hipStream_t stream)
{
    const float* X    = (const float*)d_in[0];
    const float* h0   = (const float*)d_in[1];
    const float* c0   = (const float*)d_in[2];
    const float* Wih0 = (const float*)d_in[3];
    const float* Whh0 = (const float*)d_in[4];
    const float* bih0 = (const float*)d_in[5];
    const float* bhh0 = (const float*)d_in[6];
    const float* Wih1 = (const float*)d_in[7];
    const float* Whh1 = (const float*)d_in[8];
    const float* bih1 = (const float*)d_in[9];
    const float* bhh1 = (const float*)d_in[10];
    const float* Wc1  = (const float*)d_in[11];
    const float* bc1  = (const float*)d_in[12];
    const float* Wc2  = (const float*)d_in[13];
    const float* bc2  = (const float*)d_in[14];

    float* out  = (float*)d_out;
    float* ms   = out;                  // memory_state [64][4096]
    float* hnew = out + 262144;         // h_new [2][64][4096]
    float* cnew = out + 786432;         // c_new [2][64][4096]
    float* cnt  = out + 1310720;        // count [64]

    char* ws = (char*)d_ws;
    short* Xbf  = (short*)ws;                       // 512 KB
    short* H0bf = (short*)(ws + (1u << 19));        // 1 MB
    short* h1bf = (short*)(ws + 3u * (1u << 19));   // 512 KB
    short* h2bf = (short*)(ws + (1u << 21));        // 512 KB
    float* hid  = (float*)(ws + 5u * (1u << 19));   // 512 KB
    float* Pp   = (float*)(ws + 3u * (1u << 20));   // 8 MB partials (nkq=2)

    hipLaunchKernelGGL(convert_kernel, dim3(768), dim3(256), 0, stream, X, h0, Xbf, H0bf);

    // layers: nkq=2 (Wih | Whh halves), KB=4096 -> 16 tiles/block, 512 blocks
    hipLaunchKernelGGL(gemm_part_kernel, dim3(512), dim3(256), 0, stream,
                       Xbf, H0bf, Wih0, Whh0, Pp, 16384, 2, 4096);
    hipLaunchKernelGGL(cell_kernel, dim3(256), dim3(256), 0, stream,
                       Pp, 2, bih0, bhh0, c0, hnew, cnew, (float*)nullptr, h1bf);

    hipLaunchKernelGGL(gemm_part_kernel, dim3(512), dim3(256), 0, stream,
                       h1bf, H0bf + 262144, Wih1, Whh1, Pp, 16384, 2, 4096);
    hipLaunchKernelGGL(cell_kernel, dim3(256), dim3(256), 0, stream,
                       Pp, 2, bih1, bhh1, c0 + 262144, hnew + 262144, cnew + 262144, ms, h2bf);

    // head: N=2048, K=4096 -> halves of 2048, nkq=8, KB=512, 256 blocks
    hipLaunchKernelGGL(gemm_part_kernel, dim3(256), dim3(256), 0, stream,
                       h2bf, h2bf + 2048, Wc1, Wc1 + 2048, Pp, 2048, 8, 512);
    hipLaunchKernelGGL(headfin_kernel, dim3(128), dim3(256), 0, stream, Pp, 8, bc1, hid);
    hipLaunchKernelGGL(count_kernel, dim3(1), dim3(256), 0, stream, hid, Wc2, bc2, cnt);
}